// Round 1
// baseline (1210.211 us; speedup 1.0000x reference)
//
#include <hip/hip_runtime.h>

namespace {

constexpr int kS = 1024;
constexpr int kD = 64;
constexpr int kH = 128;

__device__ __forceinline__ float fast_tanh(float x) {
  // tanh(x) = (e^{2x}-1)/(e^{2x}+1), clamped so e stays finite.
  x = fminf(fmaxf(x, -15.f), 15.f);
  float e = __expf(2.f * x);
  return (e - 1.f) * __builtin_amdgcn_rcpf(e + 1.f);
}

// Persistent bidirectional RNN.
// grid = 256 blocks: blockIdx>>7 = dir (0 fw, 1 bw), (blockIdx&127) = batch pair.
// block = 256 threads: tid>>7 = local batch (2 rows/block), tid&127 = hidden j.
// Whh row (128f) + Wih row (64f) live in registers; h state + x_t staged in LDS
// (broadcast reads only). h history journaled 32 steps deep, drained by wave 0.
__global__ __launch_bounds__(256, 1) void birnn_kernel(
    const float* __restrict__ inputs,
    const float* __restrict__ Wih_fw, const float* __restrict__ Whh_fw,
    const float* __restrict__ bih_fw, const float* __restrict__ bhh_fw,
    const float* __restrict__ Wih_bw, const float* __restrict__ Whh_bw,
    const float* __restrict__ bih_bw, const float* __restrict__ bhh_bw,
    const float* __restrict__ fcW, const float* __restrict__ fcb,
    float* __restrict__ out) {
  const int dir = blockIdx.x >> 7;
  const int b0 = (blockIdx.x & 127) * 2;
  const int tid = threadIdx.x;
  const int bl = tid >> 7;
  const int j = tid & 127;

  const float* __restrict__ Wih = dir ? Wih_bw : Wih_fw;
  const float* __restrict__ Whh = dir ? Whh_bw : Whh_fw;
  const float* __restrict__ bih = dir ? bih_bw : bih_fw;
  const float* __restrict__ bhh = dir ? bhh_bw : bhh_fw;

  __shared__ float hbuf[2][2][kH];      // double-buffered h state
  __shared__ float xlds[2][2][kD];      // double-buffered x_t
  __shared__ float fcwl[kH];            // fc weights for this direction
  __shared__ float hh[2][kH][33];       // 32-step h history (+1 pad: conflict-free)

  // ---- weight rows into registers ----
  float wh[kH];
  {
    const float4* p = (const float4*)(Whh + j * kH);
#pragma unroll
    for (int i = 0; i < kH / 4; ++i) {
      float4 v = p[i];
      wh[4 * i + 0] = v.x; wh[4 * i + 1] = v.y;
      wh[4 * i + 2] = v.z; wh[4 * i + 3] = v.w;
    }
  }
  float wi[kD];
  {
    const float4* p = (const float4*)(Wih + j * kD);
#pragma unroll
    for (int i = 0; i < kD / 4; ++i) {
      float4 v = p[i];
      wi[4 * i + 0] = v.x; wi[4 * i + 1] = v.y;
      wi[4 * i + 2] = v.z; wi[4 * i + 3] = v.w;
    }
  }
  const float bias = bih[j] + bhh[j];
  const float fcb0 = fcb[0];
  if (tid < kH) fcwl[tid] = fcW[dir * kH + tid];
  hbuf[0][bl][j] = 0.f;  // h init

  // ---- x prefetch mapping (threads 0..127): r=row, tq=time-quarter, dq=d-quad ----
  const int r = (tid >> 6) & 1;
  const int rem = tid & 63;
  const int tq = rem >> 4;
  const int dq = rem & 15;
  const float* xrow = inputs + (b0 + r) * kS * kD + dq * 4;
  float4 xA = make_float4(0.f, 0.f, 0.f, 0.f);
  float4 xB = make_float4(0.f, 0.f, 0.f, 0.f);
  if (tid < 128) {  // block covering iters 0..3
    int t2 = dir ? (kS - 1 - tq) : tq;
    xB = *(const float4*)(xrow + t2 * kD);
  }

  for (int i = 0; i < kS; ++i) {
    const int par = i & 1;
    const int q = i & 3;
    if (q == 0) {  // rotate x buffers; prefetch iters i+4..i+7 (~4 steps in flight)
      xA = xB;
      if (tid < 128) {
        int ii2 = i + 4 + tq;
        ii2 = ii2 < kS ? ii2 : kS - 1;  // clamped: harmless dup load at tail
        int t2 = dir ? (kS - 1 - ii2) : ii2;
        xB = *(const float4*)(xrow + t2 * kD);
      }
    }
    if (tid < 128 && tq == q) {  // stage this step's x into LDS
      ((float4*)&xlds[par][r][0])[dq] = xA;
    }
    __syncthreads();  // x_t and h_{t-1} visible

    // ---- drain fc-dot for the previous 32 steps (wave 0 only) ----
    if (i && (i & 31) == 0) {
      if (tid < 64) {
        const int bl2 = tid >> 5;
        const int tt = tid & 31;
        float v = 0.f;
#pragma unroll 8
        for (int k = 0; k < kH; ++k) v = fmaf(fcwl[k], hh[bl2][k][tt], v);
        const int ii = i - 32 + tt;
        const int td = dir ? (kS - 1 - ii) : ii;
        if (dir == 0) v += fcb0;
        atomicAdd(&out[(b0 + bl2) * kS + td], v);
      }
      __syncthreads();  // drain reads done before slot 0 is overwritten below
    }

    // ---- acc = bias + Wih_j . x_t + Whh_j . h  (4 chains, issue-bound) ----
    float a0 = bias, a1 = 0.f, a2 = 0.f, a3 = 0.f;
    const float4* xv = (const float4*)&xlds[par][bl][0];
#pragma unroll
    for (int k = 0; k < kD / 4; ++k) {
      float4 x4 = xv[k];
      a0 = fmaf(wi[4 * k + 0], x4.x, a0);
      a1 = fmaf(wi[4 * k + 1], x4.y, a1);
      a2 = fmaf(wi[4 * k + 2], x4.z, a2);
      a3 = fmaf(wi[4 * k + 3], x4.w, a3);
    }
    const float4* hv = (const float4*)&hbuf[par][bl][0];
#pragma unroll
    for (int k = 0; k < kH / 4; ++k) {
      float4 h4 = hv[k];
      a0 = fmaf(wh[4 * k + 0], h4.x, a0);
      a1 = fmaf(wh[4 * k + 1], h4.y, a1);
      a2 = fmaf(wh[4 * k + 2], h4.z, a2);
      a3 = fmaf(wh[4 * k + 3], h4.w, a3);
    }
    const float hnew = fast_tanh((a0 + a1) + (a2 + a3));
    hbuf[par ^ 1][bl][j] = hnew;  // state for next step (other buffer: no extra barrier)
    hh[bl][j][i & 31] = hnew;     // journal for fc drain
  }

  // ---- final drain: last 32 steps ----
  __syncthreads();
  if (tid < 64) {
    const int bl2 = tid >> 5;
    const int tt = tid & 31;
    float v = 0.f;
#pragma unroll 8
    for (int k = 0; k < kH; ++k) v = fmaf(fcwl[k], hh[bl2][k][tt], v);
    const int ii = kS - 32 + tt;
    const int td = dir ? (kS - 1 - ii) : ii;
    if (dir == 0) v += fcb0;
    atomicAdd(&out[(b0 + bl2) * kS + td], v);
  }
}

}  // namespace

extern "C" void kernel_launch(void* const* d_in, const int* in_sizes, int n_in,
                              void* d_out, int out_size, void* d_ws, size_t ws_size,
                              hipStream_t stream) {
  (void)in_sizes; (void)n_in; (void)d_ws; (void)ws_size;
  const float* inputs = (const float*)d_in[0];
  const float* Wih_fw = (const float*)d_in[1];
  const float* Whh_fw = (const float*)d_in[2];
  const float* bih_fw = (const float*)d_in[3];
  const float* bhh_fw = (const float*)d_in[4];
  const float* Wih_bw = (const float*)d_in[5];
  const float* Whh_bw = (const float*)d_in[6];
  const float* bih_bw = (const float*)d_in[7];
  const float* bhh_bw = (const float*)d_in[8];
  const float* fc_W   = (const float*)d_in[9];
  const float* fc_b   = (const float*)d_in[10];
  float* out = (float*)d_out;

  // fw and bw blocks each atomicAdd their half of the fc dot — zero first.
  hipMemsetAsync(out, 0, (size_t)out_size * sizeof(float), stream);

  dim3 grid(256), block(256);
  hipLaunchKernelGGL(birnn_kernel, grid, block, 0, stream,
                     inputs, Wih_fw, Whh_fw, bih_fw, bhh_fw,
                     Wih_bw, Whh_bw, bih_bw, bhh_bw, fc_W, fc_b, out);
}

// Round 2
// 711.469 us; speedup vs baseline: 1.7010x; 1.7010x over previous
//
#include <hip/hip_runtime.h>

namespace {

constexpr int kS = 1024;
constexpr int kD = 64;
constexpr int kH = 128;

__device__ __forceinline__ float fast_tanh(float x) {
  x = fminf(fmaxf(x, -15.f), 15.f);
  float e = __expf(2.f * x);
  return (e - 1.f) * __builtin_amdgcn_rcpf(e + 1.f);
}

__device__ __forceinline__ float dot4(float4 w, float4 v, float a) {
  a = fmaf(w.x, v.x, a);
  a = fmaf(w.y, v.y, a);
  a = fmaf(w.z, v.z, a);
  return fmaf(w.w, v.w, a);
}

// cross-lane exchange helpers: xor4 via ds_swizzle (BitMode xor=4), xor2/xor1
// via DPP quad_perm (VALU pipe — keeps LDS pipe free for the h/x reads).
__device__ __forceinline__ float lane_xor4(float v) {
  return __int_as_float(__builtin_amdgcn_ds_swizzle(__float_as_int(v), 0x101F));
}
#if __has_builtin(__builtin_amdgcn_mov_dpp)
__device__ __forceinline__ float lane_xor2(float v) {
  return __int_as_float(__builtin_amdgcn_mov_dpp(__float_as_int(v), 0x4E, 0xF, 0xF, true));
}
__device__ __forceinline__ float lane_xor1(float v) {
  return __int_as_float(__builtin_amdgcn_mov_dpp(__float_as_int(v), 0xB1, 0xF, 0xF, true));
}
#else
__device__ __forceinline__ float lane_xor2(float v) {
  return __int_as_float(__builtin_amdgcn_ds_swizzle(__float_as_int(v), 0x081F));
}
__device__ __forceinline__ float lane_xor1(float v) {
  return __int_as_float(__builtin_amdgcn_ds_swizzle(__float_as_int(v), 0x041F));
}
#endif
__device__ __forceinline__ float swz_xor1(float v) {
  return __int_as_float(__builtin_amdgcn_ds_swizzle(__float_as_int(v), 0x041F));
}
__device__ __forceinline__ float swz_xor2(float v) {
  return __int_as_float(__builtin_amdgcn_ds_swizzle(__float_as_int(v), 0x081F));
}

#define FOREACH_M(F) F(0) F(1) F(2) F(3) F(4) F(5) F(6) F(7)

// Persistent bidirectional RNN, O=8 outputs x P=8 K-split per thread.
// grid 256: dir = blockIdx>>7, batch pair = blockIdx&127 (2 rows/block).
// block 256: r = tid>>7 (row), g = (tid>>3)&15 (output group), p = tid&7 (K slice).
// Thread holds Whh[g+16m][16p..16p+16) and Wih[g+16m][8p..8p+8) for m=0..7 in
// 48 NAMED float4 registers (R1 showed arrays get demoted -> cache streaming).
// Per step: 6 conflict-free ds_read_b128 (padded slice layouts), 192 FMAs,
// 3-stage butterfly reduce over p; lane p finalizes output j=g+16p.
__global__ __launch_bounds__(256, 1) void birnn_kernel(
    const float* __restrict__ inputs,
    const float* __restrict__ Wih_fw, const float* __restrict__ Whh_fw,
    const float* __restrict__ bih_fw, const float* __restrict__ bhh_fw,
    const float* __restrict__ Wih_bw, const float* __restrict__ Whh_bw,
    const float* __restrict__ bih_bw, const float* __restrict__ bhh_bw,
    const float* __restrict__ fcW, const float* __restrict__ fcb,
    float* __restrict__ out) {
  const int dir = blockIdx.x >> 7;
  const int b0 = (blockIdx.x & 127) * 2;
  const int tid = threadIdx.x;
  const int r = tid >> 7;
  const int g = (tid >> 3) & 15;
  const int p = tid & 7;

  const float* __restrict__ Wih = dir ? Wih_bw : Wih_fw;
  const float* __restrict__ Whh = dir ? Whh_bw : Whh_fw;
  const float* __restrict__ bih = dir ? bih_bw : bih_fw;
  const float* __restrict__ bhh = dir ? bhh_bw : bhh_fw;

  // h state: 8 slices of 16 floats, each slice padded to 20 floats so the 8
  // per-wave b128 reads land on disjoint bank groups (p*20%32 all distinct/4).
  __shared__ float hbuf[2][2][160];
  // x_t: 8 slices of 8 floats padded to 12 (p*12%32 disjoint groups), 8-deep ring.
  __shared__ float xring[8][2][96];
  __shared__ float fcwl[kH];
  __shared__ float hh[2][32][132];  // 32-step h journal, inner pad 132

  // ---- weights into named registers ----
#define DECLS(m) float4 wh0_##m, wh1_##m, wh2_##m, wh3_##m, wi0_##m, wi1_##m;
  FOREACH_M(DECLS)
#undef DECLS
#define LOADS(m)                                                         \
  {                                                                      \
    const float4* wp = (const float4*)(Whh + (g + 16 * m) * kH + 16 * p);\
    wh0_##m = wp[0]; wh1_##m = wp[1]; wh2_##m = wp[2]; wh3_##m = wp[3];  \
    const float4* ip = (const float4*)(Wih + (g + 16 * m) * kD + 8 * p); \
    wi0_##m = ip[0]; wi1_##m = ip[1];                                    \
  }
  FOREACH_M(LOADS)
#undef LOADS

  const int jfin = g + 16 * p;  // output this lane finalizes
  const float bias = bih[jfin] + bhh[jfin];
  const float fcb0 = fcb[0];
  if (tid < kH) fcwl[tid] = fcW[dir * kH + tid];
  hbuf[0][r][p * 20 + g] = 0.f;  // h0 = 0 (pads never read)

  // ---- x staging: 128 threads, q = step-in-quad, rr = row, d4 = float4 idx ----
  const int q = tid >> 5;          // valid for tid<128
  const int rr = (tid >> 4) & 1;
  const int d4 = tid & 15;
  const float* xrow = inputs + (size_t)(b0 + rr) * kS * kD + d4 * 4;
  float4 xB = make_float4(0.f, 0.f, 0.f, 0.f);
  if (tid < 128) {
    int t2 = dir ? (kS - 1 - q) : q;
    xB = *(const float4*)(xrow + t2 * kD);
  }
  __syncthreads();

  for (int i = 0; i < kS; ++i) {
    if ((i & 3) == 0) {  // write held 4-step x block, issue next load (8 ahead)
      if (tid < 128) {
        const int slot = ((i >> 2) & 1) * 4 + q;
        *(float4*)&xring[slot][rr][(d4 >> 1) * 12 + (d4 & 1) * 4] = xB;
        int ii = i + 4 + q;
        if (ii > kS - 1) ii = kS - 1;
        int t2 = dir ? (kS - 1 - ii) : ii;
        xB = *(const float4*)(xrow + t2 * kD);
      }
    }
    __syncthreads();  // h(i-1), x(i) visible

    if ((i & 31) == 0 && i) {  // fc drain for steps i-32..i-1 (all 256 threads)
      const int item = tid >> 2, kp = tid & 3;
      const int r2 = item >> 5, c = item & 31;
      float v = 0.f;
      const float4* jp = (const float4*)&hh[r2][c][kp * 32];
      const float4* fp = (const float4*)&fcwl[kp * 32];
#pragma unroll
      for (int k4 = 0; k4 < 8; ++k4) v = dot4(fp[k4], jp[k4], v);
      v += swz_xor1(v);
      v += swz_xor2(v);
      if (kp == 0) {
        const int ii = i - 32 + c;
        const int td = dir ? (kS - 1 - ii) : ii;
        if (dir == 0) v += fcb0;
        atomicAdd(&out[(b0 + r2) * kS + td], v);
      }
      __syncthreads();  // journal slot (i&31) re-written below
    }

    // ---- per-thread partial dots: 8 outputs x 24 floats ----
    const float4* hp = (const float4*)(&hbuf[i & 1][r][0] + p * 20);
    const float4 h0 = hp[0], h1 = hp[1], h2 = hp[2], h3 = hp[3];
    const int slot = ((i >> 2) & 1) * 4 + (i & 3);
    const float4* xp = (const float4*)(&xring[slot][r][0] + p * 12);
    const float4 x0 = xp[0], x1 = xp[1];
#define COMP(m)                                                   \
  float s_##m = dot4(wh3_##m, h3,                                  \
                dot4(wh2_##m, h2,                                  \
                dot4(wh1_##m, h1,                                  \
                dot4(wh0_##m, h0,                                  \
                dot4(wi1_##m, x1, dot4(wi0_##m, x0, 0.f))))));
    FOREACH_M(COMP)
#undef COMP

    // ---- 3-stage value-halving butterfly over p; lane p ends with output g+16p
    const bool hi4 = (p & 4) != 0, hi2 = (p & 2) != 0, hi1 = (p & 1) != 0;
    float k0 = (hi4 ? s_4 : s_0) + lane_xor4(hi4 ? s_0 : s_4);
    float k1 = (hi4 ? s_5 : s_1) + lane_xor4(hi4 ? s_1 : s_5);
    float k2 = (hi4 ? s_6 : s_2) + lane_xor4(hi4 ? s_2 : s_6);
    float k3 = (hi4 ? s_7 : s_3) + lane_xor4(hi4 ? s_3 : s_7);
    float n0 = (hi2 ? k2 : k0) + lane_xor2(hi2 ? k0 : k2);
    float n1 = (hi2 ? k3 : k1) + lane_xor2(hi2 ? k1 : k3);
    float v = (hi1 ? n1 : n0) + lane_xor1(hi1 ? n0 : n1);

    const float hn = fast_tanh(v + bias);
    hbuf[(i & 1) ^ 1][r][p * 20 + g] = hn;  // next-step state (parity buffer)
    hh[r][i & 31][jfin] = hn;               // fc journal
  }

  // ---- final fc drain: steps S-32..S-1 ----
  __syncthreads();
  {
    const int item = tid >> 2, kp = tid & 3;
    const int r2 = item >> 5, c = item & 31;
    float v = 0.f;
    const float4* jp = (const float4*)&hh[r2][c][kp * 32];
    const float4* fp = (const float4*)&fcwl[kp * 32];
#pragma unroll
    for (int k4 = 0; k4 < 8; ++k4) v = dot4(fp[k4], jp[k4], v);
    v += swz_xor1(v);
    v += swz_xor2(v);
    if (kp == 0) {
      const int ii = kS - 32 + c;
      const int td = dir ? (kS - 1 - ii) : ii;
      if (dir == 0) v += fcb0;
      atomicAdd(&out[(b0 + r2) * kS + td], v);
    }
  }
}

#undef FOREACH_M

}  // namespace

extern "C" void kernel_launch(void* const* d_in, const int* in_sizes, int n_in,
                              void* d_out, int out_size, void* d_ws, size_t ws_size,
                              hipStream_t stream) {
  (void)in_sizes; (void)n_in; (void)d_ws; (void)ws_size;
  const float* inputs = (const float*)d_in[0];
  const float* Wih_fw = (const float*)d_in[1];
  const float* Whh_fw = (const float*)d_in[2];
  const float* bih_fw = (const float*)d_in[3];
  const float* bhh_fw = (const float*)d_in[4];
  const float* Wih_bw = (const float*)d_in[5];
  const float* Whh_bw = (const float*)d_in[6];
  const float* bih_bw = (const float*)d_in[7];
  const float* bhh_bw = (const float*)d_in[8];
  const float* fc_W   = (const float*)d_in[9];
  const float* fc_b   = (const float*)d_in[10];
  float* out = (float*)d_out;

  hipMemsetAsync(out, 0, (size_t)out_size * sizeof(float), stream);

  dim3 grid(256), block(256);
  hipLaunchKernelGGL(birnn_kernel, grid, block, 0, stream,
                     inputs, Wih_fw, Whh_fw, bih_fw, bhh_fw,
                     Wih_bw, Whh_bw, bih_bw, bhh_bw, fc_W, fc_b, out);
}